// Round 13
// baseline (599.058 us; speedup 1.0000x reference)
//
#include <hip/hip_runtime.h>

typedef unsigned short u16;
typedef unsigned int   u32;
typedef __bf16 bf16x8 __attribute__((ext_vector_type(8)));
typedef float  f32x4  __attribute__((ext_vector_type(4)));

#define NTOK   8192
#define NSLOT  16384

// ---- workspace layout (bytes) ----
#define XB_OFF   0UL           // x as bf16 [8192][1024]            16 MB
#define WIT_OFF  16777216UL    // wi^T bf16 [8][1024 d][1024 h]     16 MB
#define WOT_OFF  33554432UL    // wo^T bf16 [8][1024 o][1024 d]     16 MB
#define HB_OFF   50331648UL    // H bf16 [16384][1024]              32 MB
#define RE_OFF   83886080UL    // route_e int[16384]
#define RP_OFF   83951616UL    // route_p float[16384]
#define SEG_OFF  84017152UL    // seg int[16384]
#define META_OFF 84082688UL
// META: offs[9]@64, cursors[8]@128, ntiles@192, tile_e[136]@256, tile_r0[136]@1024
#define ZB_OFF   (META_OFF + 4096UL)   // zbuf float[8192]
#define WS_NEED  (ZB_OFF + 32768UL)

__device__ __forceinline__ u16 f2b(float f) {
  u32 u = __float_as_uint(f);
  u32 r = (u + 0x7fffu + ((u >> 16) & 1u)) >> 16;   // RNE
  return (u16)r;
}

__device__ __forceinline__ void async_cp16(const void* g, void* l) {
  __builtin_amdgcn_global_load_lds(
      (const __attribute__((address_space(1))) u32*)g,
      (__attribute__((address_space(3))) u32*)l, 16, 0, 0);
}

__device__ __forceinline__ float gelu_f(float v) {
  float u  = 0.7978845608028654f * (v + 0.044715f * v * v * v);
  float ex = __expf(2.0f * u);
  float th = 1.0f - 2.0f / (ex + 1.0f);
  return 0.5f * v * (1.0f + th);
}

// ---------- fused prep: transpose (blocks 0..4095) + router (4096..4607) ----------
__global__ __launch_bounds__(256) void k_prep(const float* __restrict__ wi,
    const float* __restrict__ wo, u16* __restrict__ wit, u16* __restrict__ wot,
    const float* __restrict__ x, const float* __restrict__ rw,
    const float* __restrict__ rb, u16* __restrict__ xb,
    int* __restrict__ route_e, float* __restrict__ route_p,
    float* __restrict__ zbuf) {
  int bid = blockIdx.x;
  int tid = threadIdx.x;
  if (bid < 4096) {
    __shared__ float t[64][65];
    int e = (bid >> 8) & 7;
    const float* src = ((bid < 2048) ? wi : wo) + ((size_t)e << 20);
    u16* dst = ((bid < 2048) ? wit : wot) + ((size_t)e << 20);
    int h0 = ((bid >> 4) & 15) * 64, d0 = (bid & 15) * 64;
#pragma unroll
    for (int j = 0; j < 4; j++) {
      int f = tid + 256 * j;
      int r = f >> 4, c4 = f & 15;
      float4 v = *(const float4*)&src[(size_t)(h0 + r) * 1024 + d0 + c4 * 4];
      t[r][c4 * 4 + 0] = v.x; t[r][c4 * 4 + 1] = v.y;
      t[r][c4 * 4 + 2] = v.z; t[r][c4 * 4 + 3] = v.w;
    }
    __syncthreads();
#pragma unroll
    for (int j = 0; j < 4; j++) {
      int f = tid + 256 * j;
      int d = f >> 4, c4 = f & 15;
      u32 p0 = (u32)f2b(t[c4 * 4 + 0][d]) | ((u32)f2b(t[c4 * 4 + 1][d]) << 16);
      u32 p1 = (u32)f2b(t[c4 * 4 + 2][d]) | ((u32)f2b(t[c4 * 4 + 3][d]) << 16);
      u32* dp = (u32*)&dst[(size_t)(d0 + d) * 1024 + h0 + c4 * 4];
      dp[0] = p0; dp[1] = p1;
    }
  } else {
    int wv = (bid - 4096) * 4 + (tid >> 6);   // 0..2047
    int l = tid & 63;
#pragma unroll 1
    for (int t4 = 0; t4 < 4; t4++) {
      int tok = wv * 4 + t4;
      const float* xrow = x + (size_t)tok * 1024;
      u16* xbrow = xb + (size_t)tok * 1024;
      float a[8] = {0.f, 0.f, 0.f, 0.f, 0.f, 0.f, 0.f, 0.f};
#pragma unroll
      for (int j = 0; j < 16; j++) {
        int c = j * 64 + l;
        float xj = xrow[c];
        xbrow[c] = f2b(xj);
        float4 w0 = *(const float4*)&rw[c * 8];
        float4 w1 = *(const float4*)&rw[c * 8 + 4];
        a[0] += xj * w0.x; a[1] += xj * w0.y; a[2] += xj * w0.z; a[3] += xj * w0.w;
        a[4] += xj * w1.x; a[5] += xj * w1.y; a[6] += xj * w1.z; a[7] += xj * w1.w;
      }
#pragma unroll
      for (int e = 0; e < 8; e++)
#pragma unroll
        for (int off = 32; off; off >>= 1) a[e] += __shfl_xor(a[e], off, 64);
      if (l == 0) {
#pragma unroll
        for (int e = 0; e < 8; e++) a[e] += rb[e];
        int e0 = 0; float b0 = a[0];
#pragma unroll
        for (int k = 1; k < 8; k++) if (a[k] > b0) { b0 = a[k]; e0 = k; }
        int e1 = -1; float b1 = -3.4e38f;
#pragma unroll
        for (int k = 0; k < 8; k++) { if (k == e0) continue; if (a[k] > b1) { b1 = a[k]; e1 = k; } }
        float s = 0.f;
#pragma unroll
        for (int k = 0; k < 8; k++) s += __expf(a[k] - b0);
        float lse = b0 + __logf(s);
        float q1 = __expf(b1 - b0);
        route_e[tok * 2 + 0] = e0; route_e[tok * 2 + 1] = e1;
        route_p[tok * 2 + 0] = 1.0f / (1.0f + q1);
        route_p[tok * 2 + 1] = q1 / (1.0f + q1);
        zbuf[tok] = lse * lse;
      }
    }
  }
}

// ---------- scan: count (LDS atomics), offsets, cursors, 128-row tiles, z ----------
__global__ __launch_bounds__(256) void k_scan(
    const int* __restrict__ route_e, int* __restrict__ offs,
    int* __restrict__ cursors, int* __restrict__ ntiles,
    int* __restrict__ tile_e, int* __restrict__ tile_r0,
    const float* __restrict__ zbuf, float* __restrict__ zout) {
  __shared__ int cnt[8];
  __shared__ float zs[4];
  int tid = threadIdx.x;
  if (tid < 8) cnt[tid] = 0;
  __syncthreads();
  for (int i = tid; i < NSLOT; i += 256) atomicAdd(&cnt[route_e[i]], 1);
  float z = 0.f;
  for (int i = tid; i < NTOK; i += 256) z += zbuf[i];
#pragma unroll
  for (int off = 32; off; off >>= 1) z += __shfl_xor(z, off, 64);
  if ((tid & 63) == 0) zs[tid >> 6] = z;
  __syncthreads();
  if (tid == 0) {
    *zout = (zs[0] + zs[1] + zs[2] + zs[3]) * (0.001f / 8192.0f);
    int o = 0, nt = 0;
    offs[0] = 0;
    for (int e = 0; e < 8; e++) {
      int c = cnt[e];
      cursors[e] = o;
      for (int r = 0; r < c; r += 128) { tile_e[nt] = e; tile_r0[nt] = o + r; nt++; }
      o += c;
      offs[e + 1] = o;
    }
    *ntiles = nt;   // <= 135 always
  }
}

// ---------- scatter with per-wave aggregated atomics (64 blocks) ----------
__global__ __launch_bounds__(256) void k_scatter(const int* __restrict__ route_e,
                                                 int* __restrict__ cursors,
                                                 int* __restrict__ seg) {
  int i = blockIdx.x * 256 + threadIdx.x;   // < 16384
  int e = route_e[i];
  int lane = threadIdx.x & 63;
#pragma unroll
  for (int ex = 0; ex < 8; ex++) {
    unsigned long long mask = __ballot(e == ex);
    if (e == ex) {
      int cnt = __popcll(mask);
      int leader = __ffsll((long long)mask) - 1;
      int base = 0;
      if (lane == leader) base = atomicAdd(&cursors[ex], cnt);
      base = __shfl(base, leader, 64);
      int rank = __popcll(mask & ((1ull << lane) - 1ull));
      seg[base + rank] = i;
    }
  }
}

// ====== 128x256x64 grouped GEMM, m97-structure (R7/R12 body) ======
// + LDS-coalesced epilogue: acc -> Bs (dead after last barrier) -> full-row
//   128/256B stores. Kills the 32/64B-granule write amplification
//   (WRITE_SIZE 75MB for 32MB hb; 184MB for 64MB out).

#define STAGE_ALL(KT)                                                    \
  do {                                                                   \
    async_cp16(asrc[0] + (KT) * 64, &As[(w * 16 + 0) * 64]);             \
    async_cp16(asrc[1] + (KT) * 64, &As[(w * 16 + 8) * 64]);             \
    async_cp16(bsrc[0] + (KT) * 64, &Bs[(w * 32 + 0) * 64]);             \
    async_cp16(bsrc[1] + (KT) * 64, &Bs[(w * 32 + 8) * 64]);             \
    async_cp16(bsrc[2] + (KT) * 64, &Bs[(w * 32 + 16) * 64]);            \
    async_cp16(bsrc[3] + (KT) * 64, &Bs[(w * 32 + 24) * 64]);            \
  } while (0)

#define GEMM_BODY()                                                                \
  _Pragma("unroll 1")                                                              \
  for (int kt = 0; kt < 16; kt++) {                                                \
    STAGE_ALL(kt);                                                                 \
    __syncthreads();                                                               \
    _Pragma("unroll")                                                              \
    for (int kk = 0; kk < 2; kk++) {                                               \
      int c = ((kk * 4 + rh) ^ (rl & 7)) * 8;                                      \
      bf16x8 af[4], bfr[4];                                                        \
      _Pragma("unroll")                                                            \
      for (int m = 0; m < 4; m++)                                                  \
        af[m] = *(const bf16x8*)&As[(wr * 64 + m * 16 + rl) * 64 + c];             \
      _Pragma("unroll")                                                            \
      for (int n = 0; n < 4; n++)                                                  \
        bfr[n] = *(const bf16x8*)&Bs[(wc * 64 + n * 16 + rl) * 64 + c];            \
      _Pragma("unroll")                                                            \
      for (int m = 0; m < 4; m++)                                                  \
        _Pragma("unroll")                                                          \
        for (int n = 0; n < 4; n++)                                                \
          acc[m][n] = __builtin_amdgcn_mfma_f32_16x16x32_bf16(af[m], bfr[n],       \
                                                              acc[m][n], 0, 0, 0); \
    }                                                                              \
    __syncthreads();                                                               \
  }

// ---------- GEMM1: H = gelu(gather(x) @ wi + bi), bf16 out ----------
__global__ __launch_bounds__(512) void k_gemm_h(
    const u16* __restrict__ xb, const u16* __restrict__ wit, const float* __restrict__ wib,
    u16* __restrict__ hb, const int* __restrict__ seg, const int* __restrict__ offs,
    const int* __restrict__ tile_e, const int* __restrict__ tile_r0,
    const int* __restrict__ ntiles) {
  __shared__ u16 As[128 * 64];
  __shared__ u16 Bs[256 * 64];
  int bid = blockIdx.x;                         // 544 blocks, XCD-chunked swizzle
  int swz = (bid & 7) * 68 + (bid >> 3);
  int mt = swz >> 2;
  if (mt >= *ntiles) return;
  int n0 = (swz & 3) << 8;
  int e = tile_e[mt], r0 = tile_r0[mt], end = offs[e + 1];
  int tid = threadIdx.x;
  int w = tid >> 6, l = tid & 63;
  int lr = l >> 3, lc = l & 7;
  int cs = lc ^ lr;                             // pre-swizzled source chunk (T2)
  const u16* asrc[2];
  const u16* bsrc[4];
#pragma unroll
  for (int j = 0; j < 2; j++) {
    int gr = r0 + w * 16 + j * 8 + lr;
    int idx = seg[(gr < end) ? gr : r0];
    asrc[j] = xb + (size_t)(idx >> 1) * 1024 + cs * 8;
  }
#pragma unroll
  for (int j = 0; j < 4; j++)
    bsrc[j] = wit + ((size_t)e << 20) + (size_t)(n0 + w * 32 + j * 8 + lr) * 1024 + cs * 8;
  f32x4 acc[4][4];
  f32x4 z4 = {0.f, 0.f, 0.f, 0.f};
#pragma unroll
  for (int m = 0; m < 4; m++)
#pragma unroll
    for (int n = 0; n < 4; n++) acc[m][n] = z4;
  int wr = w >> 2, wc = w & 3;
  int rl = l & 15, rh = l >> 4;
  GEMM_BODY()
  // --- LDS-coalesced epilogue (Bs dead after final barrier) ---
  float bias4[4];
#pragma unroll
  for (int n = 0; n < 4; n++)
    bias4[n] = wib[e * 1024 + n0 + wc * 64 + n * 16 + rl];
  u16* Cs = &Bs[w * 1024];          // per-wave 16 x 64 bf16 staging (2 KB)
#pragma unroll 1
  for (int m = 0; m < 4; m++) {
#pragma unroll
    for (int n = 0; n < 4; n++)
#pragma unroll
      for (int j = 0; j < 4; j++)
        Cs[(rh * 4 + j) * 64 + n * 16 + rl] = f2b(gelu_f(acc[m][n][j] + bias4[n]));
    asm volatile("s_waitcnt lgkmcnt(0)" ::: "memory");
#pragma unroll
    for (int p2 = 0; p2 < 2; p2++) {
      int rr = p2 * 8 + (l >> 3);
      int gr = r0 + wr * 64 + m * 16 + rr;
      uint4 v = *(const uint4*)&Cs[rr * 64 + (l & 7) * 8];
      if (gr < end)
        *(uint4*)&hb[(size_t)gr * 1024 + n0 + wc * 64 + (l & 7) * 8] = v;
    }
    asm volatile("s_waitcnt lgkmcnt(0)" ::: "memory");
  }
}

// ---------- GEMM2: out[idx] = (H @ wo + bo) * p, scattered ----------
__global__ __launch_bounds__(512) void k_gemm_o(
    const u16* __restrict__ hb, const u16* __restrict__ wot, const float* __restrict__ wob,
    float* __restrict__ out, const int* __restrict__ seg, const int* __restrict__ offs,
    const int* __restrict__ tile_e, const int* __restrict__ tile_r0,
    const int* __restrict__ ntiles, const float* __restrict__ route_p) {
  __shared__ u16 As[128 * 64];
  __shared__ u16 Bs[256 * 64];
  int bid = blockIdx.x;
  int swz = (bid & 7) * 68 + (bid >> 3);
  int mt = swz >> 2;
  if (mt >= *ntiles) return;
  int n0 = (swz & 3) << 8;
  int e = tile_e[mt], r0 = tile_r0[mt], end = offs[e + 1];
  int tid = threadIdx.x;
  int w = tid >> 6, l = tid & 63;
  int lr = l >> 3, lc = l & 7;
  int cs = lc ^ lr;
  const u16* asrc[2];
  const u16* bsrc[4];
#pragma unroll
  for (int j = 0; j < 2; j++) {
    int gr = r0 + w * 16 + j * 8 + lr;
    int grc = (gr < end) ? gr : r0;
    asrc[j] = hb + (size_t)grc * 1024 + cs * 8;   // H is segment-ordered: contiguous
  }
#pragma unroll
  for (int j = 0; j < 4; j++)
    bsrc[j] = wot + ((size_t)e << 20) + (size_t)(n0 + w * 32 + j * 8 + lr) * 1024 + cs * 8;
  f32x4 acc[4][4];
  f32x4 z4 = {0.f, 0.f, 0.f, 0.f};
#pragma unroll
  for (int m = 0; m < 4; m++)
#pragma unroll
    for (int n = 0; n < 4; n++) acc[m][n] = z4;
  int wr = w >> 2, wc = w & 3;
  int rl = l & 15, rh = l >> 4;
  GEMM_BODY()
  // --- LDS-coalesced epilogue (fp32): per-wave 16 x 64 f32 staging (4 KB) ---
  float bias4[4];
#pragma unroll
  for (int n = 0; n < 4; n++)
    bias4[n] = wob[e * 1024 + n0 + wc * 64 + n * 16 + rl];
  float* Cs = (float*)&Bs[0] + w * 1024;
#pragma unroll 1
  for (int m = 0; m < 4; m++) {
#pragma unroll
    for (int j = 0; j < 4; j++) {
      int gr = r0 + wr * 64 + m * 16 + rh * 4 + j;
      int grc = (gr < end) ? gr : r0;
      float p = route_p[seg[grc]];
#pragma unroll
      for (int n = 0; n < 4; n++)
        Cs[(rh * 4 + j) * 64 + n * 16 + rl] = (acc[m][n][j] + bias4[n]) * p;
    }
    asm volatile("s_waitcnt lgkmcnt(0)" ::: "memory");
#pragma unroll
    for (int p4 = 0; p4 < 4; p4++) {
      int rr = p4 * 4 + (l >> 4);
      int gr = r0 + wr * 64 + m * 16 + rr;
      float4 v = *(const float4*)&Cs[rr * 64 + (l & 15) * 4];
      if (gr < end) {
        int idx = seg[gr];
        *(float4*)&out[(size_t)idx * 1024 + n0 + wc * 64 + (l & 15) * 4] = v;
      }
    }
    asm volatile("s_waitcnt lgkmcnt(0)" ::: "memory");
  }
}

extern "C" void kernel_launch(void* const* d_in, const int* in_sizes, int n_in,
                              void* d_out, int out_size, void* d_ws, size_t ws_size,
                              hipStream_t stream) {
  if (ws_size < WS_NEED) return;
  const float* x   = (const float*)d_in[0];
  const float* rw  = (const float*)d_in[1];
  const float* rb  = (const float*)d_in[2];
  const float* wiw = (const float*)d_in[3];
  const float* wib = (const float*)d_in[4];
  const float* wow = (const float*)d_in[5];
  const float* wob = (const float*)d_in[6];
  float* out = (float*)d_out;
  char* ws = (char*)d_ws;

  u16*   xb      = (u16*)(ws + XB_OFF);
  u16*   wit     = (u16*)(ws + WIT_OFF);
  u16*   wot     = (u16*)(ws + WOT_OFF);
  u16*   hb      = (u16*)(ws + HB_OFF);
  int*   route_e = (int*)(ws + RE_OFF);
  float* route_p = (float*)(ws + RP_OFF);
  int*   seg     = (int*)(ws + SEG_OFF);
  int*   offs    = (int*)(ws + META_OFF + 64);
  int*   cursors = (int*)(ws + META_OFF + 128);
  int*   ntiles  = (int*)(ws + META_OFF + 192);
  int*   tile_e  = (int*)(ws + META_OFF + 256);
  int*   tile_r0 = (int*)(ws + META_OFF + 1024);
  float* zbuf    = (float*)(ws + ZB_OFF);

  k_prep<<<4608, 256, 0, stream>>>(wiw, wow, wit, wot, x, rw, rb, xb,
                                   route_e, route_p, zbuf);
  k_scan<<<1, 256, 0, stream>>>(route_e, offs, cursors, ntiles, tile_e, tile_r0,
                                zbuf, out + (out_size - 1));
  k_scatter<<<64, 256, 0, stream>>>(route_e, cursors, seg);
  k_gemm_h<<<544, 512, 0, stream>>>(xb, wit, wib, hb, seg, offs,
                                    tile_e, tile_r0, ntiles);
  k_gemm_o<<<544, 512, 0, stream>>>(hb, wot, wob, out, seg, offs,
                                    tile_e, tile_r0, ntiles, route_p);
}

// Round 14
// 216.186 us; speedup vs baseline: 2.7710x; 2.7710x over previous
//
#include <hip/hip_runtime.h>

typedef unsigned short u16;
typedef unsigned int   u32;
typedef __bf16 bf16x8 __attribute__((ext_vector_type(8)));
typedef float  f32x4  __attribute__((ext_vector_type(4)));

#define NTOK   8192
#define NSLOT  16384

// ---- workspace layout (bytes) ----
#define XB_OFF   0UL           // x as bf16 [8192][1024]            16 MB
#define WIT_OFF  16777216UL    // wi^T bf16 [8][1024 d][1024 h]     16 MB
#define WOT_OFF  33554432UL    // wo^T bf16 [8][1024 o][1024 d]     16 MB
#define HB_OFF   50331648UL    // H bf16 [16384][1024]              32 MB
#define RE_OFF   83886080UL    // route_e int[16384]
#define RP_OFF   83951616UL    // route_p float[16384]
#define SEG_OFF  84017152UL    // seg int[16384]
#define META_OFF 84082688UL
// META: offs[9]@64, cursors[8]@128, ntiles@192, tile_e[136]@256, tile_r0[136]@1024
#define ZB_OFF   (META_OFF + 4096UL)   // zbuf float[8192]
#define WS_NEED  (ZB_OFF + 32768UL)

__device__ __forceinline__ u16 f2b(float f) {
  u32 u = __float_as_uint(f);
  u32 r = (u + 0x7fffu + ((u >> 16) & 1u)) >> 16;   // RNE
  return (u16)r;
}

__device__ __forceinline__ void async_cp16(const void* g, void* l) {
  __builtin_amdgcn_global_load_lds(
      (const __attribute__((address_space(1))) u32*)g,
      (__attribute__((address_space(3))) u32*)l, 16, 0, 0);
}

__device__ __forceinline__ float gelu_f(float v) {
  float u  = 0.7978845608028654f * (v + 0.044715f * v * v * v);
  float ex = __expf(2.0f * u);
  float th = 1.0f - 2.0f / (ex + 1.0f);
  return 0.5f * v * (1.0f + th);
}

// ---------- fused prep: transpose (blocks 0..4095) + router (4096..4607) ----------
__global__ __launch_bounds__(256) void k_prep(const float* __restrict__ wi,
    const float* __restrict__ wo, u16* __restrict__ wit, u16* __restrict__ wot,
    const float* __restrict__ x, const float* __restrict__ rw,
    const float* __restrict__ rb, u16* __restrict__ xb,
    int* __restrict__ route_e, float* __restrict__ route_p,
    float* __restrict__ zbuf) {
  int bid = blockIdx.x;
  int tid = threadIdx.x;
  if (bid < 4096) {
    __shared__ float t[64][65];
    int e = (bid >> 8) & 7;
    const float* src = ((bid < 2048) ? wi : wo) + ((size_t)e << 20);
    u16* dst = ((bid < 2048) ? wit : wot) + ((size_t)e << 20);
    int h0 = ((bid >> 4) & 15) * 64, d0 = (bid & 15) * 64;
#pragma unroll
    for (int j = 0; j < 4; j++) {
      int f = tid + 256 * j;
      int r = f >> 4, c4 = f & 15;
      float4 v = *(const float4*)&src[(size_t)(h0 + r) * 1024 + d0 + c4 * 4];
      t[r][c4 * 4 + 0] = v.x; t[r][c4 * 4 + 1] = v.y;
      t[r][c4 * 4 + 2] = v.z; t[r][c4 * 4 + 3] = v.w;
    }
    __syncthreads();
#pragma unroll
    for (int j = 0; j < 4; j++) {
      int f = tid + 256 * j;
      int d = f >> 4, c4 = f & 15;
      u32 p0 = (u32)f2b(t[c4 * 4 + 0][d]) | ((u32)f2b(t[c4 * 4 + 1][d]) << 16);
      u32 p1 = (u32)f2b(t[c4 * 4 + 2][d]) | ((u32)f2b(t[c4 * 4 + 3][d]) << 16);
      u32* dp = (u32*)&dst[(size_t)(d0 + d) * 1024 + h0 + c4 * 4];
      dp[0] = p0; dp[1] = p1;
    }
  } else {
    int wv = (bid - 4096) * 4 + (tid >> 6);   // 0..2047
    int l = tid & 63;
#pragma unroll 1
    for (int t4 = 0; t4 < 4; t4++) {
      int tok = wv * 4 + t4;
      const float* xrow = x + (size_t)tok * 1024;
      u16* xbrow = xb + (size_t)tok * 1024;
      float a[8] = {0.f, 0.f, 0.f, 0.f, 0.f, 0.f, 0.f, 0.f};
#pragma unroll
      for (int j = 0; j < 16; j++) {
        int c = j * 64 + l;
        float xj = xrow[c];
        xbrow[c] = f2b(xj);
        float4 w0 = *(const float4*)&rw[c * 8];
        float4 w1 = *(const float4*)&rw[c * 8 + 4];
        a[0] += xj * w0.x; a[1] += xj * w0.y; a[2] += xj * w0.z; a[3] += xj * w0.w;
        a[4] += xj * w1.x; a[5] += xj * w1.y; a[6] += xj * w1.z; a[7] += xj * w1.w;
      }
#pragma unroll
      for (int e = 0; e < 8; e++)
#pragma unroll
        for (int off = 32; off; off >>= 1) a[e] += __shfl_xor(a[e], off, 64);
      if (l == 0) {
#pragma unroll
        for (int e = 0; e < 8; e++) a[e] += rb[e];
        int e0 = 0; float b0 = a[0];
#pragma unroll
        for (int k = 1; k < 8; k++) if (a[k] > b0) { b0 = a[k]; e0 = k; }
        int e1 = -1; float b1 = -3.4e38f;
#pragma unroll
        for (int k = 0; k < 8; k++) { if (k == e0) continue; if (a[k] > b1) { b1 = a[k]; e1 = k; } }
        float s = 0.f;
#pragma unroll
        for (int k = 0; k < 8; k++) s += __expf(a[k] - b0);
        float lse = b0 + __logf(s);
        float q1 = __expf(b1 - b0);
        route_e[tok * 2 + 0] = e0; route_e[tok * 2 + 1] = e1;
        route_p[tok * 2 + 0] = 1.0f / (1.0f + q1);
        route_p[tok * 2 + 1] = q1 / (1.0f + q1);
        zbuf[tok] = lse * lse;
      }
    }
  }
}

// ---------- scan: count (LDS atomics), offsets, cursors, 128-row tiles, z ----------
__global__ __launch_bounds__(256) void k_scan(
    const int* __restrict__ route_e, int* __restrict__ offs,
    int* __restrict__ cursors, int* __restrict__ ntiles,
    int* __restrict__ tile_e, int* __restrict__ tile_r0,
    const float* __restrict__ zbuf, float* __restrict__ zout) {
  __shared__ int cnt[8];
  __shared__ float zs[4];
  int tid = threadIdx.x;
  if (tid < 8) cnt[tid] = 0;
  __syncthreads();
  for (int i = tid; i < NSLOT; i += 256) atomicAdd(&cnt[route_e[i]], 1);
  float z = 0.f;
  for (int i = tid; i < NTOK; i += 256) z += zbuf[i];
#pragma unroll
  for (int off = 32; off; off >>= 1) z += __shfl_xor(z, off, 64);
  if ((tid & 63) == 0) zs[tid >> 6] = z;
  __syncthreads();
  if (tid == 0) {
    *zout = (zs[0] + zs[1] + zs[2] + zs[3]) * (0.001f / 8192.0f);
    int o = 0, nt = 0;
    offs[0] = 0;
    for (int e = 0; e < 8; e++) {
      int c = cnt[e];
      cursors[e] = o;
      for (int r = 0; r < c; r += 128) { tile_e[nt] = e; tile_r0[nt] = o + r; nt++; }
      o += c;
      offs[e + 1] = o;
    }
    *ntiles = nt;   // <= 135 always
  }
}

// ---------- scatter with per-wave aggregated atomics (64 blocks) ----------
__global__ __launch_bounds__(256) void k_scatter(const int* __restrict__ route_e,
                                                 int* __restrict__ cursors,
                                                 int* __restrict__ seg) {
  int i = blockIdx.x * 256 + threadIdx.x;   // < 16384
  int e = route_e[i];
  int lane = threadIdx.x & 63;
#pragma unroll
  for (int ex = 0; ex < 8; ex++) {
    unsigned long long mask = __ballot(e == ex);
    if (e == ex) {
      int cnt = __popcll(mask);
      int leader = __ffsll((long long)mask) - 1;
      int base = 0;
      if (lane == leader) base = atomicAdd(&cursors[ex], cnt);
      base = __shfl(base, leader, 64);
      int rank = __popcll(mask & ((1ull << lane) - 1ull));
      seg[base + rank] = i;
    }
  }
}

// ====== 128x256x64 grouped GEMM, m97-structure (R7/R12 body — best measured) ======
// 512 threads = 8 waves (2M x 4N); per-wave 64x64 out (4x4 frags).
// LDS: A 16K + B 32K = 48 KiB single-buffered; grid 544 (~2.1 blocks/CU
// co-resident) -> barrier drains hidden by sibling-block compute (m114).

#define STAGE_ALL(KT)                                                    \
  do {                                                                   \
    async_cp16(asrc[0] + (KT) * 64, &As[(w * 16 + 0) * 64]);             \
    async_cp16(asrc[1] + (KT) * 64, &As[(w * 16 + 8) * 64]);             \
    async_cp16(bsrc[0] + (KT) * 64, &Bs[(w * 32 + 0) * 64]);             \
    async_cp16(bsrc[1] + (KT) * 64, &Bs[(w * 32 + 8) * 64]);             \
    async_cp16(bsrc[2] + (KT) * 64, &Bs[(w * 32 + 16) * 64]);            \
    async_cp16(bsrc[3] + (KT) * 64, &Bs[(w * 32 + 24) * 64]);            \
  } while (0)

#define GEMM_BODY()                                                                \
  _Pragma("unroll 1")                                                              \
  for (int kt = 0; kt < 16; kt++) {                                                \
    STAGE_ALL(kt);                                                                 \
    __syncthreads();                                                               \
    _Pragma("unroll")                                                              \
    for (int kk = 0; kk < 2; kk++) {                                               \
      int c = ((kk * 4 + rh) ^ (rl & 7)) * 8;                                      \
      bf16x8 af[4], bfr[4];                                                        \
      _Pragma("unroll")                                                            \
      for (int m = 0; m < 4; m++)                                                  \
        af[m] = *(const bf16x8*)&As[(wr * 64 + m * 16 + rl) * 64 + c];             \
      _Pragma("unroll")                                                            \
      for (int n = 0; n < 4; n++)                                                  \
        bfr[n] = *(const bf16x8*)&Bs[(wc * 64 + n * 16 + rl) * 64 + c];            \
      _Pragma("unroll")                                                            \
      for (int m = 0; m < 4; m++)                                                  \
        _Pragma("unroll")                                                          \
        for (int n = 0; n < 4; n++)                                                \
          acc[m][n] = __builtin_amdgcn_mfma_f32_16x16x32_bf16(af[m], bfr[n],       \
                                                              acc[m][n], 0, 0, 0); \
    }                                                                              \
    __syncthreads();                                                               \
  }

// ---------- GEMM1: H = gelu(gather(x) @ wi + bi), bf16 out ----------
__global__ __launch_bounds__(512) void k_gemm_h(
    const u16* __restrict__ xb, const u16* __restrict__ wit, const float* __restrict__ wib,
    u16* __restrict__ hb, const int* __restrict__ seg, const int* __restrict__ offs,
    const int* __restrict__ tile_e, const int* __restrict__ tile_r0,
    const int* __restrict__ ntiles) {
  __shared__ u16 As[128 * 64];
  __shared__ u16 Bs[256 * 64];
  int bid = blockIdx.x;                         // 544 blocks, XCD-chunked swizzle
  int swz = (bid & 7) * 68 + (bid >> 3);
  int mt = swz >> 2;
  if (mt >= *ntiles) return;
  int n0 = (swz & 3) << 8;
  int e = tile_e[mt], r0 = tile_r0[mt], end = offs[e + 1];
  int tid = threadIdx.x;
  int w = tid >> 6, l = tid & 63;
  int lr = l >> 3, lc = l & 7;
  int cs = lc ^ lr;                             // pre-swizzled source chunk (T2)
  const u16* asrc[2];
  const u16* bsrc[4];
#pragma unroll
  for (int j = 0; j < 2; j++) {
    int gr = r0 + w * 16 + j * 8 + lr;
    int idx = seg[(gr < end) ? gr : r0];
    asrc[j] = xb + (size_t)(idx >> 1) * 1024 + cs * 8;
  }
#pragma unroll
  for (int j = 0; j < 4; j++)
    bsrc[j] = wit + ((size_t)e << 20) + (size_t)(n0 + w * 32 + j * 8 + lr) * 1024 + cs * 8;
  f32x4 acc[4][4];
  f32x4 z4 = {0.f, 0.f, 0.f, 0.f};
#pragma unroll
  for (int m = 0; m < 4; m++)
#pragma unroll
    for (int n = 0; n < 4; n++) acc[m][n] = z4;
  int wr = w >> 2, wc = w & 3;
  int rl = l & 15, rh = l >> 4;
  GEMM_BODY()
#pragma unroll
  for (int n = 0; n < 4; n++) {
    int col = n0 + wc * 64 + n * 16 + rl;
    float bias = wib[e * 1024 + col];
#pragma unroll
    for (int m = 0; m < 4; m++) {
      int rbase = r0 + wr * 64 + m * 16 + rh * 4;
#pragma unroll
      for (int j = 0; j < 4; j++) {
        int gr = rbase + j;
        if (gr < end)
          hb[(size_t)gr * 1024 + col] = f2b(gelu_f(acc[m][n][j] + bias));
      }
    }
  }
}

// ---------- GEMM2: out[idx] = (H @ wo + bo) * p, scattered ----------
__global__ __launch_bounds__(512) void k_gemm_o(
    const u16* __restrict__ hb, const u16* __restrict__ wot, const float* __restrict__ wob,
    float* __restrict__ out, const int* __restrict__ seg, const int* __restrict__ offs,
    const int* __restrict__ tile_e, const int* __restrict__ tile_r0,
    const int* __restrict__ ntiles, const float* __restrict__ route_p) {
  __shared__ u16 As[128 * 64];
  __shared__ u16 Bs[256 * 64];
  int bid = blockIdx.x;
  int swz = (bid & 7) * 68 + (bid >> 3);
  int mt = swz >> 2;
  if (mt >= *ntiles) return;
  int n0 = (swz & 3) << 8;
  int e = tile_e[mt], r0 = tile_r0[mt], end = offs[e + 1];
  int tid = threadIdx.x;
  int w = tid >> 6, l = tid & 63;
  int lr = l >> 3, lc = l & 7;
  int cs = lc ^ lr;
  const u16* asrc[2];
  const u16* bsrc[4];
#pragma unroll
  for (int j = 0; j < 2; j++) {
    int gr = r0 + w * 16 + j * 8 + lr;
    int grc = (gr < end) ? gr : r0;
    asrc[j] = hb + (size_t)grc * 1024 + cs * 8;   // H is segment-ordered: contiguous
  }
#pragma unroll
  for (int j = 0; j < 4; j++)
    bsrc[j] = wot + ((size_t)e << 20) + (size_t)(n0 + w * 32 + j * 8 + lr) * 1024 + cs * 8;
  f32x4 acc[4][4];
  f32x4 z4 = {0.f, 0.f, 0.f, 0.f};
#pragma unroll
  for (int m = 0; m < 4; m++)
#pragma unroll
    for (int n = 0; n < 4; n++) acc[m][n] = z4;
  int wr = w >> 2, wc = w & 3;
  int rl = l & 15, rh = l >> 4;
  GEMM_BODY()
#pragma unroll
  for (int m = 0; m < 4; m++) {
    int rbase = r0 + wr * 64 + m * 16 + rh * 4;
#pragma unroll
    for (int j = 0; j < 4; j++) {
      int gr = rbase + j;
      if (gr >= end) continue;
      int idx = seg[gr];
      float p = route_p[idx];
      float* orow = out + (size_t)idx * 1024;
#pragma unroll
      for (int n = 0; n < 4; n++) {
        int col = n0 + wc * 64 + n * 16 + rl;
        orow[col] = (acc[m][n][j] + wob[e * 1024 + col]) * p;
      }
    }
  }
}

extern "C" void kernel_launch(void* const* d_in, const int* in_sizes, int n_in,
                              void* d_out, int out_size, void* d_ws, size_t ws_size,
                              hipStream_t stream) {
  if (ws_size < WS_NEED) return;
  const float* x   = (const float*)d_in[0];
  const float* rw  = (const float*)d_in[1];
  const float* rb  = (const float*)d_in[2];
  const float* wiw = (const float*)d_in[3];
  const float* wib = (const float*)d_in[4];
  const float* wow = (const float*)d_in[5];
  const float* wob = (const float*)d_in[6];
  float* out = (float*)d_out;
  char* ws = (char*)d_ws;

  u16*   xb      = (u16*)(ws + XB_OFF);
  u16*   wit     = (u16*)(ws + WIT_OFF);
  u16*   wot     = (u16*)(ws + WOT_OFF);
  u16*   hb      = (u16*)(ws + HB_OFF);
  int*   route_e = (int*)(ws + RE_OFF);
  float* route_p = (float*)(ws + RP_OFF);
  int*   seg     = (int*)(ws + SEG_OFF);
  int*   offs    = (int*)(ws + META_OFF + 64);
  int*   cursors = (int*)(ws + META_OFF + 128);
  int*   ntiles  = (int*)(ws + META_OFF + 192);
  int*   tile_e  = (int*)(ws + META_OFF + 256);
  int*   tile_r0 = (int*)(ws + META_OFF + 1024);
  float* zbuf    = (float*)(ws + ZB_OFF);

  k_prep<<<4608, 256, 0, stream>>>(wiw, wow, wit, wot, x, rw, rb, xb,
                                   route_e, route_p, zbuf);
  k_scan<<<1, 256, 0, stream>>>(route_e, offs, cursors, ntiles, tile_e, tile_r0,
                                zbuf, out + (out_size - 1));
  k_scatter<<<64, 256, 0, stream>>>(route_e, cursors, seg);
  k_gemm_h<<<544, 512, 0, stream>>>(xb, wit, wib, hb, seg, offs,
                                    tile_e, tile_r0, ntiles);
  k_gemm_o<<<544, 512, 0, stream>>>(hb, wot, wob, out, seg, offs,
                                    tile_e, tile_r0, ntiles, route_p);
}